// Round 6
// baseline (285.132 us; speedup 1.0000x reference)
//
#include <hip/hip_runtime.h>
#include <hip/hip_bf16.h>
#include <hip/hip_fp16.h>

typedef _Float16 f16x8  __attribute__((ext_vector_type(8)));
typedef __fp16   h16x2  __attribute__((ext_vector_type(2)));
typedef float    f32x4  __attribute__((ext_vector_type(4)));
typedef float    f32x16 __attribute__((ext_vector_type(16)));

#define KDIM      384
#define MBLK      64
#define NEDGE     800000
#define HRPAD     136
#define WQ_ELEMS  16384      // 8 ks * 4 nt * 64 lanes * 8
#define WRP_ELEMS 4096

__device__ __forceinline__ float fast_swish(float v) {
  return v * __builtin_amdgcn_rcpf(1.0f + __expf(-v));
}

// ---- Pack W_lin cols 256..383 (rbf part) into 32x32x16 A-fragments, f16;
//      and W_rbf into the 16x16x32 rbf B-fragments (K padded 6->32).
__global__ void pack_w_kernel(const float* __restrict__ W_lin,
                              const float* __restrict__ W_rbf,
                              _Float16* __restrict__ Wq,
                              _Float16* __restrict__ Wrp) {
  int idx = blockIdx.x * 256 + threadIdx.x;
  if (idx < WQ_ELEMS) {
    int e  = idx & 7;
    int l  = (idx >> 3) & 63;
    int nt = (idx >> 9) & 3;
    int ks = idx >> 11;                        // 0..7
    int n  = nt * 32 + (l & 31);
    int k  = 256 + ks * 16 + ((l >> 5) << 3) + e;
    Wq[idx] = (_Float16)W_lin[n * KDIM + k];
  } else if (idx < WQ_ELEMS + WRP_ELEMS) {
    int idx2 = idx - WQ_ELEMS;
    int e  = idx2 & 7;
    int l  = (idx2 >> 3) & 63;
    int nt = idx2 >> 9;
    int k  = ((l >> 4) << 3) + e;
    float v = (k < 6) ? W_rbf[(nt * 16 + (l & 15)) * 6 + k] : 0.0f;
    Wrp[idx2] = (_Float16)v;
  }
}

// ---- Tiny factor tables, exact f32:
// PRi[r][c] = sum_k W_lin[c][k]    * resi_w[r][k]  + b_lin[c]   (r<20)
// PAi[r][c] = sum_k W_lin[c][64+k] * atom_w[r][k]               (r<95)
// PRj[r][c] = sum_k W_lin[c][128+k]* resi_w[r][k]               (r<20)
// PAj[r][c] = sum_k W_lin[c][192+k]* atom_w[r][k]               (r<95)
__global__ void prep_p_kernel(const float* __restrict__ W_lin,
                              const float* __restrict__ resi_w,
                              const float* __restrict__ atom_w,
                              const float* __restrict__ b_lin,
                              float* __restrict__ P) {   // PRi|PAi|PRj|PAj
  int idx = blockIdx.x * 256 + threadIdx.x;
  if (idx >= 230 * 128) return;
  int c = idx & 127;
  int r = idx >> 7;                 // 0..229
  const float* T;
  int woff;
  float s = 0.0f;
  float* dst;
  if (r < 20)       { T = resi_w + r * 64;         woff = 0;   s = b_lin[c]; dst = P + r * 128; }
  else if (r < 115) { T = atom_w + (r - 20) * 64;  woff = 64;  dst = P + (20 * 128)  + (r - 20) * 128; }
  else if (r < 135) { T = resi_w + (r - 115) * 64; woff = 128; dst = P + (115 * 128) + (r - 115) * 128; }
  else              { T = atom_w + (r - 135) * 64; woff = 192; dst = P + (135 * 128) + (r - 135) * 128; }
  const float4* W4 = (const float4*)(W_lin + c * KDIM + woff);
  const float4* T4 = (const float4*)T;
  #pragma unroll
  for (int k = 0; k < 16; ++k) {
    float4 wv = W4[k], tv = T4[k];
    s += wv.x * tv.x + wv.y * tv.y + wv.z * tv.z + wv.w * tv.w;
  }
  dst[c] = s;
}

__global__ __launch_bounds__(256, 4)
void edge_kernel(const float* __restrict__ rbf,
                 const int* __restrict__ gi,
                 const int* __restrict__ gj,
                 const int* __restrict__ x,
                 const float* __restrict__ b_rbf,
                 const _Float16* __restrict__ Wq,
                 const _Float16* __restrict__ Wrp,
                 const float* __restrict__ P,
                 float* __restrict__ out) {
  __shared__ alignas(16) _Float16 hr[MBLK][HRPAD];   // rbf_h tile, 17.4 KB
  const int tid  = threadIdx.x;
  const int e0   = blockIdx.x * MBLK;
  const int lane = tid & 63;
  const int wave = tid >> 6;
  const int s    = wave & 1;          // edge strip (32 edges)
  const int p    = wave >> 1;         // nt pair: cols {64p..64p+63}
  const int c5   = lane & 31;
  const int g2   = lane >> 5;

  const float* PRi = P;
  const float* PAi = P + 20 * 128;
  const float* PRj = P + 115 * 128;
  const float* PAj = P + 135 * 128;

  // ---- Early: index chains for this lane's edge
  const int e  = e0 + s * 32 + c5;
  const int ni = gi[e];
  const int nj = gj[e];
  int2 xi = *(const int2*)(x + 2 * ni);
  int2 xj = *(const int2*)(x + 2 * nj);
  const float* pri = PRi + xi.x * 128;
  const float* pai = PAi + xi.y * 128;
  const float* prj = PRj + xj.x * 128;
  const float* paj = PAj + xj.y * 128;

  // ---- rbf_h = swish(rbf @ W_rbf^T + b_rbf), 16x16x32 MFMA -> LDS (f16)
  {
    const int g = lane >> 4;
    const int c = lane & 15;
    f16x8 ra = {0, 0, 0, 0, 0, 0, 0, 0};
    if (g == 0) {
      const float* rp = rbf + (size_t)(e0 + wave * 16 + c) * 6;
      ra[0] = (_Float16)rp[0]; ra[1] = (_Float16)rp[1]; ra[2] = (_Float16)rp[2];
      ra[3] = (_Float16)rp[3]; ra[4] = (_Float16)rp[4]; ra[5] = (_Float16)rp[5];
    }
    const f16x8* wrb = (const f16x8*)Wrp + lane;
    #pragma unroll
    for (int nt = 0; nt < 8; ++nt) {
      f16x8 rb = wrb[nt * 64];
      f32x4 d = __builtin_amdgcn_mfma_f32_16x16x32_f16(ra, rb,
                  (f32x4){0.f, 0.f, 0.f, 0.f}, 0, 0, 0);
      float bb = b_rbf[nt * 16 + c];
      #pragma unroll
      for (int r = 0; r < 4; ++r) {
        float vv = d[r] + bb;
        hr[wave * 16 + 4 * g + r][nt * 16 + c] = (_Float16)fast_swish(vv);
      }
    }
  }
  __syncthreads();

  // ---- Qr = rbf_h @ W_r^T, K=128, swapped operands: D cols = edges
  const f16x8* wq = (const f16x8*)Wq + lane;
  const _Float16* hbase = &hr[s * 32 + c5][g2 << 3];
  f32x16 acc0 = {};
  f32x16 acc1 = {};
  #pragma unroll
  for (int ks = 0; ks < 8; ++ks) {
    f16x8 b = *(const f16x8*)(hbase + ks * 16);
    acc0 = __builtin_amdgcn_mfma_f32_32x32x16_f16(wq[(ks * 4 + 2 * p) * 64],     b, acc0, 0, 0, 0);
    acc1 = __builtin_amdgcn_mfma_f32_32x32x16_f16(wq[(ks * 4 + 2 * p + 1) * 64], b, acc1, 0, 0, 0);
  }

  // ---- Epilogue: out[e][chan] = swish(acc + PRi + PAi + PRj + PAj)
  // D: col=lane&31 (edge), row=(reg&3)+8*(reg>>2)+4*g2 (chan within 32-tile)
  float* orow = out + (size_t)e * 128;
  #pragma unroll
  for (int t = 0; t < 2; ++t) {
    const int cb = 64 * p + 32 * t;
    float4 a_[4], b_[4], c_[4], d_[4];
    #pragma unroll
    for (int q = 0; q < 4; ++q) {
      int c0 = cb + 8 * q + 4 * g2;
      a_[q] = *(const float4*)(pri + c0);
      b_[q] = *(const float4*)(pai + c0);
      c_[q] = *(const float4*)(prj + c0);
      d_[q] = *(const float4*)(paj + c0);
    }
    #pragma unroll
    for (int q = 0; q < 4; ++q) {
      int c0 = cb + 8 * q + 4 * g2;
      float4 o;
      float v0, v1, v2, v3;
      if (t == 0) {
        v0 = acc0[4 * q]; v1 = acc0[4 * q + 1]; v2 = acc0[4 * q + 2]; v3 = acc0[4 * q + 3];
      } else {
        v0 = acc1[4 * q]; v1 = acc1[4 * q + 1]; v2 = acc1[4 * q + 2]; v3 = acc1[4 * q + 3];
      }
      o.x = fast_swish(v0 + a_[q].x + b_[q].x + c_[q].x + d_[q].x);
      o.y = fast_swish(v1 + a_[q].y + b_[q].y + c_[q].y + d_[q].y);
      o.z = fast_swish(v2 + a_[q].z + b_[q].z + c_[q].z + d_[q].z);
      o.w = fast_swish(v3 + a_[q].w + b_[q].w + c_[q].w + d_[q].w);
      *(float4*)(orow + c0) = o;
    }
  }
}

extern "C" void kernel_launch(void* const* d_in, const int* in_sizes, int n_in,
                              void* d_out, int out_size, void* d_ws, size_t ws_size,
                              hipStream_t stream) {
  const int*   x      = (const int*)d_in[0];
  const float* rbf    = (const float*)d_in[1];
  const int*   gi     = (const int*)d_in[2];
  const int*   gj     = (const int*)d_in[3];
  const float* resi_w = (const float*)d_in[4];
  const float* atom_w = (const float*)d_in[5];
  const float* W_rbf  = (const float*)d_in[6];
  const float* b_rbf  = (const float*)d_in[7];
  const float* W_lin  = (const float*)d_in[8];
  const float* b_lin  = (const float*)d_in[9];
  float* out = (float*)d_out;

  _Float16* Wq  = (_Float16*)d_ws;                           // 32 KB
  _Float16* Wrp = (_Float16*)d_ws + WQ_ELEMS;                // 8 KB
  float*    P   = (float*)((char*)d_ws + (WQ_ELEMS + WRP_ELEMS) * 2);  // 115 KB

  hipLaunchKernelGGL(pack_w_kernel, dim3((WQ_ELEMS + WRP_ELEMS) / 256), dim3(256), 0, stream,
                     W_lin, W_rbf, Wq, Wrp);
  hipLaunchKernelGGL(prep_p_kernel, dim3((230 * 128 + 255) / 256), dim3(256), 0, stream,
                     W_lin, resi_w, atom_w, b_lin, P);
  hipLaunchKernelGGL(edge_kernel, dim3(NEDGE / MBLK), dim3(256), 0, stream,
                     rbf, gi, gj, x, b_rbf, Wq, Wrp, P, out);
}